// Round 5
// baseline (435.913 us; speedup 1.0000x reference)
//
#include <hip/hip_runtime.h>
#include <math.h>

typedef _Float16 half_t;
typedef __attribute__((ext_vector_type(8))) _Float16 half8;
typedef __attribute__((ext_vector_type(16))) float floatx16;

__device__ __forceinline__ float gelu_exact(float v) {
    return 0.5f * v * (1.0f + erff(v * 0.7071067811865476f));
}

__device__ __forceinline__ floatx16 zero16() {
    floatx16 z;
#pragma unroll
    for (int i = 0; i < 16; ++i) z[i] = 0.f;
    return z;
}

#define MFMA16(a, b, c) __builtin_amdgcn_mfma_f32_32x32x16_f16((a), (b), (c), 0, 0, 0)

// ---------------- prep ---------------- (unchanged; layout validated)
__global__ __launch_bounds__(256) void prep(const float* __restrict__ W0,
                                            const float* __restrict__ A0,
                                            const float* __restrict__ W1,
                                            const float* __restrict__ A1,
                                            half_t* __restrict__ Wsw0, half_t* __restrict__ Wsw1,
                                            half_t* __restrict__ Zah0, half_t* __restrict__ Zal0,
                                            half_t* __restrict__ Zah1, half_t* __restrict__ Zal1) {
    __shared__ float tile[32][257];
    const int t  = threadIdx.x;
    const int kb = blockIdx.x & 7;
    const int h  = (blockIdx.x >> 3) & 3;
    const int tz = blockIdx.x >> 5;
    const float* W = tz ? W1 : W0;
    const float* A = tz ? A1 : A0;
    half_t* Wsw = tz ? Wsw1 : Wsw0;
    half_t* Zh  = tz ? Zah1 : Zah0;
    half_t* Zl  = tz ? Zal1 : Zal0;

    for (int i = 0; i < 32; ++i)
        tile[i][t] = W[(size_t)(h * 256 + kb * 32 + i) * 256 + t];
    __syncthreads();

    const int j = t >> 5, lmn = t & 31;
#pragma unroll
    for (int i0 = 0; i0 < 32; i0 += 8) {
        const int ks = 2 * kb + (i0 >> 4);
        const int qq = (i0 >> 3) & 1;
        half_t hb[8];
#pragma unroll
        for (int ii = 0; ii < 8; ++ii) hb[ii] = (half_t)tile[i0 + ii][t];
        size_t off = ((size_t)(h * 16 + ks) * 8 + j) * 512 + (size_t)(32 * qq + lmn) * 8;
        *(half8*)&Wsw[off] = *(half8*)hb;
    }

    if (kb == 0) {
        const float4* Wr = (const float4*)&W[(size_t)(h * 256 + t) * 256];
        const float4* Al = (const float4*)&A[h * 512];
        const float4* Ah = (const float4*)&A[h * 512 + 256];
        float wl = 0.f, wh = 0.f;
        for (int d = 0; d < 64; ++d) {
            float4 wv = Wr[d], a0 = Al[d], a1 = Ah[d];
            wl += wv.x * a0.x + wv.y * a0.y + wv.z * a0.z + wv.w * a0.w;
            wh += wv.x * a1.x + wv.y * a1.y + wv.z * a1.z + wv.w * a1.w;
        }
        half_t hi = (half_t)wl;
        Zh[(2 * h) * 256 + t] = hi;
        Zl[(2 * h) * 256 + t] = (half_t)(wl - (float)hi);
        hi = (half_t)wh;
        Zh[(2 * h + 1) * 256 + t] = hi;
        Zl[(2 * h + 1) * 256 + t] = (half_t)(wh - (float)hi);
        if (h == 0) {
            for (int c = 8; c < 32; ++c) {
                Zh[c * 256 + t] = (half_t)0.f;
                Zl[c * 256 + t] = (half_t)0.f;
            }
        }
    }
}

// hi/lo split of one fp32 chunk into two half8 fragments
__device__ __forceinline__ void split8(const float4& v0, const float4& v1,
                                       half_t* hb, half_t* lb) {
#pragma unroll
    for (int ii = 0; ii < 8; ++ii) {
        float v = (ii < 4) ? (&v0.x)[ii] : (&v1.x)[ii - 4];
        half_t hv = (half_t)v;
        hb[ii] = hv;
        lb[ii] = (half_t)(v - (float)hv);
    }
}

// ---------------- layer 1: merged pass, canonical layout, conflict-free staging ----------------
// 64 rows/block, 256 thr, 2048 blocks, 2 blk/CU.
__global__ __launch_bounds__(256, 2) void gat1n(
    const float* __restrict__ x, const half_t* __restrict__ Wsw,
    const half_t* __restrict__ Zah, const half_t* __restrict__ Zal,
    float* __restrict__ out) {
    __shared__ __align__(16) half_t xsh[32 * 512];   // 32 KiB, canonical frag layout
    __shared__ __align__(16) half_t xsl[32 * 512];   // 32 KiB
    __shared__ float zpart[4][64][9];                // 9 KiB
    __shared__ __align__(16) float ge_s[4][64];
    __shared__ __align__(16) float att_s[4][64];

    const int t = threadIdx.x;
    const int w = t >> 6, l = t & 63, lm = t & 31, q = (t >> 5) & 1;

    // ---- staging: row-fast lane mapping -> stride-16 LDS writes (0 conflicts),
    //      canonical layout (reads become base+immediate, no extra addr regs) ----
    {
        const float4* xg = (const float4*)(x + (size_t)blockIdx.x * 64 * 256);
        const int row = t & 63;                       // lane-fast
        const int m = row >> 5, r31 = row & 31;
#pragma unroll
        for (int i = 0; i < 8; ++i) {
            const int cc = 4 * i + w;                 // wave-fixed per iteration
            const int ks = cc >> 1, kq = cc & 1;
            float4 v0 = xg[row * 64 + 2 * cc];
            float4 v1 = xg[row * 64 + 2 * cc + 1];
            half_t hb[8], lb[8];
            split8(v0, v1, hb, lb);
            int base = ((m * 16 + ks) * 64 + 32 * kq + r31) * 8;   // halves
            *(half8*)&xsh[base] = *(half8*)hb;
            *(half8*)&xsl[base] = *(half8*)lb;
        }
    }
    __syncthreads();

    // ---- z-phase: 4-way ks-split across waves, merged hi/lo into one acc ----
    {
        floatx16 zp0 = zero16(), zp1 = zero16();
#pragma unroll
        for (int kk = 0; kk < 4; ++kk) {
            int ks = 4 * w + kk;
            int ko = lm * 256 + 16 * ks + 8 * q;
            half8 bh = *(const half8*)&Zah[ko];
            half8 bl = *(const half8*)&Zal[ko];
            half8 ah0 = *(const half8*)&xsh[(ks * 64 + l) * 8];
            half8 al0 = *(const half8*)&xsl[(ks * 64 + l) * 8];
            zp0 = MFMA16(ah0, bh, zp0);
            zp0 = MFMA16(al0, bh, zp0);
            zp0 = MFMA16(ah0, bl, zp0);
            half8 ah1 = *(const half8*)&xsh[((16 + ks) * 64 + l) * 8];
            half8 al1 = *(const half8*)&xsl[((16 + ks) * 64 + l) * 8];
            zp1 = MFMA16(ah1, bh, zp1);
            zp1 = MFMA16(al1, bh, zp1);
            zp1 = MFMA16(ah1, bl, zp1);
        }
        if (lm < 8) {
#pragma unroll
            for (int r = 0; r < 16; ++r) {
                int row = 4 * q + (r & 3) + 8 * (r >> 2);
                zpart[w][row][lm]      = zp0[r];
                zpart[w][row + 32][lm] = zp1[r];
            }
        }
    }
    __syncthreads();

    {   // z reduce + double gelu (4 heads x 64 rows = all 256 threads)
        int h = t >> 6, r = t & 63;
        int c0 = 2 * h, c1 = 2 * h + 1, rr = r & ~15;
        float own  = zpart[0][r][c0] + zpart[1][r][c0] + zpart[2][r][c0] + zpart[3][r][c0];
        float root = zpart[0][rr][c1] + zpart[1][rr][c1] + zpart[2][rr][c1] + zpart[3][rr][c1];
        ge_s[h][r] = gelu_exact(gelu_exact(own + root));
    }
    __syncthreads();
    {   // softmax over each 16-row group
        int h = t >> 6, r = t & 63;
        int g0 = r & ~15;
        float mx = -1e30f;
#pragma unroll
        for (int i = 0; i < 16; ++i) mx = fmaxf(mx, ge_s[h][g0 + i]);
        float sum = 0.f;
#pragma unroll
        for (int i = 0; i < 16; ++i) sum += expf(ge_s[h][g0 + i] - mx);
        att_s[h][r] = expf(ge_s[h][r] - mx) / sum;
    }
    __syncthreads();

    // ---- merged hi/lo GEMM: B loaded once; named accs (no arrays) ----
    float outp[2][4];
#pragma unroll
    for (int nt = 0; nt < 2; ++nt)
#pragma unroll
        for (int g = 0; g < 4; ++g) outp[nt][g] = 0.f;

#pragma unroll 1
    for (int h = 0; h < 4; ++h) {
        const half_t* Bp = Wsw + ((size_t)(h * 16) * 8 + 2 * w) * 512 + (size_t)l * 8;
        floatx16 acc00 = zero16(), acc01 = zero16();
        floatx16 acc10 = zero16(), acc11 = zero16();
#pragma unroll
        for (int ks = 0; ks < 16; ++ks) {
            half8 b0 = *(const half8*)(Bp + (size_t)ks * 4096);
            half8 b1 = *(const half8*)(Bp + (size_t)ks * 4096 + 512);
            half8 ah0 = *(const half8*)&xsh[(ks * 64 + l) * 8];
            half8 al0 = *(const half8*)&xsl[(ks * 64 + l) * 8];
            acc00 = MFMA16(ah0, b0, acc00);
            acc00 = MFMA16(al0, b0, acc00);
            acc01 = MFMA16(ah0, b1, acc01);
            acc01 = MFMA16(al0, b1, acc01);
            half8 ah1 = *(const half8*)&xsh[((16 + ks) * 64 + l) * 8];
            half8 al1 = *(const half8*)&xsl[((16 + ks) * 64 + l) * 8];
            acc10 = MFMA16(ah1, b0, acc10);
            acc10 = MFMA16(al1, b0, acc10);
            acc11 = MFMA16(ah1, b1, acc11);
            acc11 = MFMA16(al1, b1, acc11);
        }

        // fold: all indices compile-time static after unrolling
        float tp0[4], tp1[4];
#pragma unroll
        for (int g = 0; g < 4; ++g) { tp0[g] = 0.f; tp1[g] = 0.f; }
#pragma unroll
        for (int k = 0; k < 4; ++k)
#pragma unroll
            for (int jj = 0; jj < 4; ++jj) {
                const int r = 4 * k + jj;
                {   // mt = 0 -> groups 0..1
                    const int g = k >> 1;
                    float av = att_s[h][4 * q + 8 * k + jj];
                    tp0[g] = fmaf(acc00[r], av, tp0[g]);
                    tp1[g] = fmaf(acc01[r], av, tp1[g]);
                }
                {   // mt = 1 -> groups 2..3
                    const int g = 2 + (k >> 1);
                    float av = att_s[h][32 + 4 * q + 8 * k + jj];
                    tp0[g] = fmaf(acc10[r], av, tp0[g]);
                    tp1[g] = fmaf(acc11[r], av, tp1[g]);
                }
            }

#pragma unroll
        for (int g = 0; g < 4; ++g) {
            float s0 = tp0[g] + __shfl_xor(tp0[g], 32, 64);
            float s1 = tp1[g] + __shfl_xor(tp1[g], 32, 64);
            outp[0][g] += gelu_exact(s0);
            outp[1][g] += gelu_exact(s1);
        }
    }

    if (q == 0) {
#pragma unroll
        for (int g = 0; g < 4; ++g) {
            size_t ro = ((size_t)blockIdx.x * 4 + g) * 256 + 64 * w;
            out[ro + lm]      = 0.25f * outp[0][g];
            out[ro + 32 + lm] = 0.25f * outp[1][g];
        }
    }
}

// ---------------- layer 2: 32 rows/block, 1024 thr, 256 blocks ----------------
// Same de-swizzled canonical scheme: transposed staging, base+imm reads.
__global__ __launch_bounds__(1024, 1) void gat2(
    const float* __restrict__ y1, const half_t* __restrict__ Wsw,
    const half_t* __restrict__ Zah, const half_t* __restrict__ Zal,
    float* __restrict__ out) {
    __shared__ __align__(16) half_t xsh[16 * 512];
    __shared__ __align__(16) half_t xsl[16 * 512];
    __shared__ float zpart[4][32][9];
    __shared__ __align__(16) float ge_s[4][32];
    __shared__ __align__(16) float att_s[4][32];
    __shared__ float outp_s[4][2][256];

    const int t = threadIdx.x;
    const int w = t >> 6, l = t & 63, lm = t & 31, q = (t >> 5) & 1;

    {   // staging: row-fast mapping, conflict-free
        const float4* xg = (const float4*)(y1 + (size_t)blockIdx.x * 32 * 256);
        const int row = t & 31;
        const int cc = t >> 5;                        // 0..31
        const int ks = cc >> 1, kq = cc & 1;
        float4 v0 = xg[row * 64 + 2 * cc];
        float4 v1 = xg[row * 64 + 2 * cc + 1];
        half_t hb[8], lb[8];
        split8(v0, v1, hb, lb);
        int base = (ks * 64 + 32 * kq + row) * 8;
        *(half8*)&xsh[base] = *(half8*)hb;
        *(half8*)&xsl[base] = *(half8*)lb;
    }
    __syncthreads();

    if (w < 4) {   // z-phase, 4-way ks split
        floatx16 zp = zero16();
#pragma unroll
        for (int kk = 0; kk < 4; ++kk) {
            int ks = 4 * w + kk;
            int ko = lm * 256 + 16 * ks + 8 * q;
            half8 bh = *(const half8*)&Zah[ko];
            half8 bl = *(const half8*)&Zal[ko];
            half8 ah = *(const half8*)&xsh[(ks * 64 + l) * 8];
            half8 al = *(const half8*)&xsl[(ks * 64 + l) * 8];
            zp = MFMA16(ah, bh, zp);
            zp = MFMA16(al, bh, zp);
            zp = MFMA16(ah, bl, zp);
        }
        if (lm < 8) {
#pragma unroll
            for (int r = 0; r < 16; ++r) {
                int row = 4 * q + (r & 3) + 8 * (r >> 2);
                zpart[w][row][lm] = zp[r];
            }
        }
    }
    __syncthreads();

    if (t < 128) {
        int h = t >> 5, r = t & 31;
        int c0 = 2 * h, c1 = 2 * h + 1, rr = r & ~15;
        float own  = zpart[0][r][c0] + zpart[1][r][c0] + zpart[2][r][c0] + zpart[3][r][c0];
        float root = zpart[0][rr][c1] + zpart[1][rr][c1] + zpart[2][rr][c1] + zpart[3][rr][c1];
        ge_s[h][r] = gelu_exact(gelu_exact(own + root));
    }
    __syncthreads();
    if (t < 128) {
        int h = t >> 5, r = t & 31;
        int g0 = r & ~15;
        float mx = -1e30f;
#pragma unroll
        for (int i = 0; i < 16; ++i) mx = fmaxf(mx, ge_s[h][g0 + i]);
        float sum = 0.f;
#pragma unroll
        for (int i = 0; i < 16; ++i) sum += expf(ge_s[h][g0 + i] - mx);
        att_s[h][r] = expf(ge_s[h][r] - mx) / sum;
    }
    __syncthreads();

    const int head = w >> 2, strip = w & 3;
    const half_t* Bp = Wsw + ((size_t)(head * 16) * 8 + 2 * strip) * 512 + (size_t)l * 8;

    floatx16 acc0 = zero16(), acc1 = zero16();
#pragma unroll
    for (int ks = 0; ks < 16; ++ks) {
        half8 b0 = *(const half8*)(Bp + (size_t)ks * 4096);
        half8 b1 = *(const half8*)(Bp + (size_t)ks * 4096 + 512);
        half8 ah = *(const half8*)&xsh[(ks * 64 + l) * 8];
        half8 al = *(const half8*)&xsl[(ks * 64 + l) * 8];
        acc0 = MFMA16(ah, b0, acc0);
        acc0 = MFMA16(al, b0, acc0);
        acc1 = MFMA16(ah, b1, acc1);
        acc1 = MFMA16(al, b1, acc1);
    }
    float tp[2][2];
    tp[0][0] = tp[0][1] = tp[1][0] = tp[1][1] = 0.f;
#pragma unroll
    for (int k2 = 0; k2 < 2; ++k2)
#pragma unroll
        for (int kk = 0; kk < 2; ++kk)
#pragma unroll
            for (int jj = 0; jj < 4; ++jj) {
                const int k = 2 * k2 + kk;
                const int r = 4 * k + jj;       // static
                const int g = k2;               // static
                float av = att_s[head][16 * g + 8 * kk + 4 * q + jj];
                tp[0][g] = fmaf(acc0[r], av, tp[0][g]);
                tp[1][g] = fmaf(acc1[r], av, tp[1][g]);
            }
#pragma unroll
    for (int nt = 0; nt < 2; ++nt)
#pragma unroll
        for (int g = 0; g < 2; ++g) {
            float s = tp[nt][g] + __shfl_xor(tp[nt][g], 32, 64);
            if (q == 0) outp_s[head][g][64 * strip + 32 * nt + lm] = gelu_exact(s);
        }
    __syncthreads();

    if (t < 512) {
        int g = t >> 8, col = t & 255;
        float s = outp_s[0][g][col] + outp_s[1][g][col] + outp_s[2][g][col] + outp_s[3][g][col];
        out[((size_t)blockIdx.x * 2 + g) * 256 + col] = 0.25f * s;
    }
}

extern "C" void kernel_launch(void* const* d_in, const int* in_sizes, int n_in,
                              void* d_out, int out_size, void* d_ws, size_t ws_size,
                              hipStream_t stream) {
    const float* x  = (const float*)d_in[0];
    const float* W0 = (const float*)d_in[1];
    const float* A0 = (const float*)d_in[2];
    const float* W1 = (const float*)d_in[3];
    const float* A1 = (const float*)d_in[4];

    char* ws = (char*)d_ws;
    float*  y1   = (float*)ws;                  // 8 MiB: [8192][256]
    half_t* Wsw0 = (half_t*)(ws + 8388608);     // 512 KiB
    half_t* Wsw1 = (half_t*)(ws + 8912896);     // 512 KiB
    half_t* Zah0 = (half_t*)(ws + 9437184);     // 16 KiB each
    half_t* Zal0 = (half_t*)(ws + 9453568);
    half_t* Zah1 = (half_t*)(ws + 9469952);
    half_t* Zal1 = (half_t*)(ws + 9486336);

    prep<<<64, 256, 0, stream>>>(W0, A0, W1, A1, Wsw0, Wsw1, Zah0, Zal0, Zah1, Zal1);
    gat1n<<<2048, 256, 0, stream>>>(x, Wsw0, Zah0, Zal0, y1);
    gat2<<<256, 1024, 0, stream>>>(y1, Wsw1, Zah1, Zal1, (float*)d_out);
}

// Round 6
// 336.644 us; speedup vs baseline: 1.2949x; 1.2949x over previous
//
#include <hip/hip_runtime.h>
#include <math.h>

typedef _Float16 half_t;
typedef __attribute__((ext_vector_type(8))) _Float16 half8;
typedef __attribute__((ext_vector_type(16))) float floatx16;

__device__ __forceinline__ float gelu_exact(float v) {
    return 0.5f * v * (1.0f + erff(v * 0.7071067811865476f));
}

__device__ __forceinline__ floatx16 zero16() {
    floatx16 z;
#pragma unroll
    for (int i = 0; i < 16; ++i) z[i] = 0.f;
    return z;
}

#define MFMA16(a, b, c) __builtin_amdgcn_mfma_f32_32x32x16_f16((a), (b), (c), 0, 0, 0)

// ---------------- prep ---------------- (unchanged; layout validated)
__global__ __launch_bounds__(256) void prep(const float* __restrict__ W0,
                                            const float* __restrict__ A0,
                                            const float* __restrict__ W1,
                                            const float* __restrict__ A1,
                                            half_t* __restrict__ Wsw0, half_t* __restrict__ Wsw1,
                                            half_t* __restrict__ Zah0, half_t* __restrict__ Zal0,
                                            half_t* __restrict__ Zah1, half_t* __restrict__ Zal1) {
    __shared__ float tile[32][257];
    const int t  = threadIdx.x;
    const int kb = blockIdx.x & 7;
    const int h  = (blockIdx.x >> 3) & 3;
    const int tz = blockIdx.x >> 5;
    const float* W = tz ? W1 : W0;
    const float* A = tz ? A1 : A0;
    half_t* Wsw = tz ? Wsw1 : Wsw0;
    half_t* Zh  = tz ? Zah1 : Zah0;
    half_t* Zl  = tz ? Zal1 : Zal0;

    for (int i = 0; i < 32; ++i)
        tile[i][t] = W[(size_t)(h * 256 + kb * 32 + i) * 256 + t];
    __syncthreads();

    const int j = t >> 5, lmn = t & 31;
#pragma unroll
    for (int i0 = 0; i0 < 32; i0 += 8) {
        const int ks = 2 * kb + (i0 >> 4);
        const int qq = (i0 >> 3) & 1;
        half_t hb[8];
#pragma unroll
        for (int ii = 0; ii < 8; ++ii) hb[ii] = (half_t)tile[i0 + ii][t];
        size_t off = ((size_t)(h * 16 + ks) * 8 + j) * 512 + (size_t)(32 * qq + lmn) * 8;
        *(half8*)&Wsw[off] = *(half8*)hb;
    }

    if (kb == 0) {
        const float4* Wr = (const float4*)&W[(size_t)(h * 256 + t) * 256];
        const float4* Al = (const float4*)&A[h * 512];
        const float4* Ah = (const float4*)&A[h * 512 + 256];
        float wl = 0.f, wh = 0.f;
        for (int d = 0; d < 64; ++d) {
            float4 wv = Wr[d], a0 = Al[d], a1 = Ah[d];
            wl += wv.x * a0.x + wv.y * a0.y + wv.z * a0.z + wv.w * a0.w;
            wh += wv.x * a1.x + wv.y * a1.y + wv.z * a1.z + wv.w * a1.w;
        }
        half_t hi = (half_t)wl;
        Zh[(2 * h) * 256 + t] = hi;
        Zl[(2 * h) * 256 + t] = (half_t)(wl - (float)hi);
        hi = (half_t)wh;
        Zh[(2 * h + 1) * 256 + t] = hi;
        Zl[(2 * h + 1) * 256 + t] = (half_t)(wh - (float)hi);
        if (h == 0) {
            for (int c = 8; c < 32; ++c) {
                Zh[c * 256 + t] = (half_t)0.f;
                Zl[c * 256 + t] = (half_t)0.f;
            }
        }
    }
}

// hi/lo split of one fp32 chunk into two half8 fragments
__device__ __forceinline__ void split8(const float4& v0, const float4& v1,
                                       half_t* hb, half_t* lb) {
#pragma unroll
    for (int ii = 0; ii < 8; ++ii) {
        float v = (ii < 4) ? (&v0.x)[ii] : (&v1.x)[ii - 4];
        half_t hv = (half_t)v;
        hb[ii] = hv;
        lb[ii] = (half_t)(v - (float)hv);
    }
}

// ---------------- layer 1: control 2-pass GEMM + conflict-free staging + 4-way z ----------------
// 64 rows/block, 256 thr, 2048 blocks, 2 blk/CU. GEMM/fold/epilogue are
// byte-identical to the proven round-0 control (no spill, WRITE 12 MB).
__global__ __launch_bounds__(256, 2) void gat1t(
    const float* __restrict__ x, const half_t* __restrict__ Wsw,
    const half_t* __restrict__ Zah, const half_t* __restrict__ Zal,
    float* __restrict__ out) {
    __shared__ __align__(16) half_t xsh[32 * 512];   // 32 KiB, canonical frag layout
    __shared__ __align__(16) half_t xsl[32 * 512];   // 32 KiB
    __shared__ float zpart[4][64][9];                // 9 KiB (pad 9 -> conflict-free reduce)
    __shared__ __align__(16) float ge_s[4][64];
    __shared__ __align__(16) float att_s[4][64];

    const int t = threadIdx.x;
    const int w = t >> 6, l = t & 63, lm = t & 31, q = (t >> 5) & 1;

    // ---- staging: row-fast lane mapping -> stride-16 LDS writes (0 conflicts),
    //      canonical layout (fragment reads stay base+immediate) ----
    {
        const float4* xg = (const float4*)(x + (size_t)blockIdx.x * 64 * 256);
        const int row = t & 63;                       // lane-fast
        const int m = row >> 5, r31 = row & 31;
#pragma unroll
        for (int i = 0; i < 8; ++i) {
            const int cc = 4 * i + w;                 // wave-fixed per iteration
            const int ks = cc >> 1, kq = cc & 1;
            float4 v0 = xg[row * 64 + 2 * cc];
            float4 v1 = xg[row * 64 + 2 * cc + 1];
            half_t hb[8], lb[8];
            split8(v0, v1, hb, lb);
            int base = ((m * 16 + ks) * 64 + 32 * kq + r31) * 8;   // halves
            *(half8*)&xsh[base] = *(half8*)hb;
            *(half8*)&xsl[base] = *(half8*)lb;
        }
    }
    __syncthreads();

    // ---- z-phase: 4-way ks-split across waves (validated r4/r5) ----
    {
        floatx16 zp0 = zero16(), zp1 = zero16();
#pragma unroll
        for (int kk = 0; kk < 4; ++kk) {
            int ks = 4 * w + kk;
            int ko = lm * 256 + 16 * ks + 8 * q;
            half8 bh = *(const half8*)&Zah[ko];
            half8 bl = *(const half8*)&Zal[ko];
            half8 ah0 = *(const half8*)&xsh[(ks * 64 + l) * 8];
            half8 al0 = *(const half8*)&xsl[(ks * 64 + l) * 8];
            zp0 = MFMA16(ah0, bh, zp0);
            zp0 = MFMA16(al0, bh, zp0);
            zp0 = MFMA16(ah0, bl, zp0);
            half8 ah1 = *(const half8*)&xsh[((16 + ks) * 64 + l) * 8];
            half8 al1 = *(const half8*)&xsl[((16 + ks) * 64 + l) * 8];
            zp1 = MFMA16(ah1, bh, zp1);
            zp1 = MFMA16(al1, bh, zp1);
            zp1 = MFMA16(ah1, bl, zp1);
        }
        if (lm < 8) {
#pragma unroll
            for (int r = 0; r < 16; ++r) {
                int row = 4 * q + (r & 3) + 8 * (r >> 2);
                zpart[w][row][lm]      = zp0[r];
                zpart[w][row + 32][lm] = zp1[r];
            }
        }
    }
    __syncthreads();

    {   // z reduce + double gelu (4 heads x 64 rows = all 256 threads)
        int h = t >> 6, r = t & 63;
        int c0 = 2 * h, c1 = 2 * h + 1, rr = r & ~15;
        float own  = zpart[0][r][c0] + zpart[1][r][c0] + zpart[2][r][c0] + zpart[3][r][c0];
        float root = zpart[0][rr][c1] + zpart[1][rr][c1] + zpart[2][rr][c1] + zpart[3][rr][c1];
        ge_s[h][r] = gelu_exact(gelu_exact(own + root));
    }
    __syncthreads();
    {   // softmax over each 16-row group
        int h = t >> 6, r = t & 63;
        int g0 = r & ~15;
        float mx = -1e30f;
#pragma unroll
        for (int i = 0; i < 16; ++i) mx = fmaxf(mx, ge_s[h][g0 + i]);
        float sum = 0.f;
#pragma unroll
        for (int i = 0; i < 16; ++i) sum += expf(ge_s[h][g0 + i] - mx);
        att_s[h][r] = expf(ge_s[h][r] - mx) / sum;
    }
    __syncthreads();

    // ---- main GEMM: EXACT round-0 control (2-pass hi/lo, proven no-spill) ----
    float outp[2][4];
#pragma unroll
    for (int nt = 0; nt < 2; ++nt)
#pragma unroll
        for (int g = 0; g < 4; ++g) outp[nt][g] = 0.f;

#pragma unroll 1
    for (int h = 0; h < 4; ++h) {
        float tp[2][4];
#pragma unroll
        for (int nt = 0; nt < 2; ++nt)
#pragma unroll
            for (int g = 0; g < 4; ++g) tp[nt][g] = 0.f;

        const half_t* Bp = Wsw + ((size_t)(h * 16) * 8 + 2 * w) * 512 + (size_t)l * 8;

#pragma unroll 1
        for (int pass = 0; pass < 2; ++pass) {
            const half_t* Xp = pass ? xsl : xsh;
            floatx16 acc[2][2];
#pragma unroll
            for (int mt = 0; mt < 2; ++mt) { acc[mt][0] = zero16(); acc[mt][1] = zero16(); }

#pragma unroll
            for (int ks = 0; ks < 16; ++ks) {
                half8 b0 = *(const half8*)(Bp + (size_t)ks * 4096);
                half8 b1 = *(const half8*)(Bp + (size_t)ks * 4096 + 512);
#pragma unroll
                for (int mt = 0; mt < 2; ++mt) {
                    half8 a = *(const half8*)&Xp[((mt * 16 + ks) * 64 + l) * 8];
                    acc[mt][0] = MFMA16(a, b0, acc[mt][0]);
                    acc[mt][1] = MFMA16(a, b1, acc[mt][1]);
                }
            }

#pragma unroll
            for (int mt = 0; mt < 2; ++mt)
#pragma unroll
                for (int k = 0; k < 4; ++k) {
                    float4 a4 = *(const float4*)&att_s[h][32 * mt + 4 * q + 8 * k];
#pragma unroll
                    for (int jj = 0; jj < 4; ++jj) {
                        int r = 4 * k + jj;
                        int row = 32 * mt + 4 * q + 8 * k + jj;
                        int g = row >> 4;
                        float av = (&a4.x)[jj];
                        tp[0][g] = fmaf(acc[mt][0][r], av, tp[0][g]);
                        tp[1][g] = fmaf(acc[mt][1][r], av, tp[1][g]);
                    }
                }
        }

#pragma unroll
        for (int nt = 0; nt < 2; ++nt)
#pragma unroll
            for (int g = 0; g < 4; ++g) {
                float s = tp[nt][g] + __shfl_xor(tp[nt][g], 32, 64);
                outp[nt][g] += gelu_exact(s);
            }
    }

    if (q == 0) {
#pragma unroll
        for (int g = 0; g < 4; ++g) {
            size_t ro = ((size_t)blockIdx.x * 4 + g) * 256 + 64 * w;
            out[ro + lm]      = 0.25f * outp[0][g];
            out[ro + 32 + lm] = 0.25f * outp[1][g];
        }
    }
}

// ---------------- layer 2: r5's 1024-thr kernel verbatim (proven passing) ----------------
__global__ __launch_bounds__(1024, 1) void gat2(
    const float* __restrict__ y1, const half_t* __restrict__ Wsw,
    const half_t* __restrict__ Zah, const half_t* __restrict__ Zal,
    float* __restrict__ out) {
    __shared__ __align__(16) half_t xsh[16 * 512];
    __shared__ __align__(16) half_t xsl[16 * 512];
    __shared__ float zpart[4][32][9];
    __shared__ __align__(16) float ge_s[4][32];
    __shared__ __align__(16) float att_s[4][32];
    __shared__ float outp_s[4][2][256];

    const int t = threadIdx.x;
    const int w = t >> 6, l = t & 63, lm = t & 31, q = (t >> 5) & 1;

    {   // staging: row-fast mapping, conflict-free
        const float4* xg = (const float4*)(y1 + (size_t)blockIdx.x * 32 * 256);
        const int row = t & 31;
        const int cc = t >> 5;                        // 0..31
        const int ks = cc >> 1, kq = cc & 1;
        float4 v0 = xg[row * 64 + 2 * cc];
        float4 v1 = xg[row * 64 + 2 * cc + 1];
        half_t hb[8], lb[8];
        split8(v0, v1, hb, lb);
        int base = (ks * 64 + 32 * kq + row) * 8;
        *(half8*)&xsh[base] = *(half8*)hb;
        *(half8*)&xsl[base] = *(half8*)lb;
    }
    __syncthreads();

    if (w < 4) {   // z-phase, 4-way ks split
        floatx16 zp = zero16();
#pragma unroll
        for (int kk = 0; kk < 4; ++kk) {
            int ks = 4 * w + kk;
            int ko = lm * 256 + 16 * ks + 8 * q;
            half8 bh = *(const half8*)&Zah[ko];
            half8 bl = *(const half8*)&Zal[ko];
            half8 ah = *(const half8*)&xsh[(ks * 64 + l) * 8];
            half8 al = *(const half8*)&xsl[(ks * 64 + l) * 8];
            zp = MFMA16(ah, bh, zp);
            zp = MFMA16(al, bh, zp);
            zp = MFMA16(ah, bl, zp);
        }
        if (lm < 8) {
#pragma unroll
            for (int r = 0; r < 16; ++r) {
                int row = 4 * q + (r & 3) + 8 * (r >> 2);
                zpart[w][row][lm] = zp[r];
            }
        }
    }
    __syncthreads();

    if (t < 128) {
        int h = t >> 5, r = t & 31;
        int c0 = 2 * h, c1 = 2 * h + 1, rr = r & ~15;
        float own  = zpart[0][r][c0] + zpart[1][r][c0] + zpart[2][r][c0] + zpart[3][r][c0];
        float root = zpart[0][rr][c1] + zpart[1][rr][c1] + zpart[2][rr][c1] + zpart[3][rr][c1];
        ge_s[h][r] = gelu_exact(gelu_exact(own + root));
    }
    __syncthreads();
    if (t < 128) {
        int h = t >> 5, r = t & 31;
        int g0 = r & ~15;
        float mx = -1e30f;
#pragma unroll
        for (int i = 0; i < 16; ++i) mx = fmaxf(mx, ge_s[h][g0 + i]);
        float sum = 0.f;
#pragma unroll
        for (int i = 0; i < 16; ++i) sum += expf(ge_s[h][g0 + i] - mx);
        att_s[h][r] = expf(ge_s[h][r] - mx) / sum;
    }
    __syncthreads();

    const int head = w >> 2, strip = w & 3;
    const half_t* Bp = Wsw + ((size_t)(head * 16) * 8 + 2 * strip) * 512 + (size_t)l * 8;

    floatx16 acc0 = zero16(), acc1 = zero16();
#pragma unroll
    for (int ks = 0; ks < 16; ++ks) {
        half8 b0 = *(const half8*)(Bp + (size_t)ks * 4096);
        half8 b1 = *(const half8*)(Bp + (size_t)ks * 4096 + 512);
        half8 ah = *(const half8*)&xsh[(ks * 64 + l) * 8];
        half8 al = *(const half8*)&xsl[(ks * 64 + l) * 8];
        acc0 = MFMA16(ah, b0, acc0);
        acc0 = MFMA16(al, b0, acc0);
        acc1 = MFMA16(ah, b1, acc1);
        acc1 = MFMA16(al, b1, acc1);
    }
    float tp[2][2];
    tp[0][0] = tp[0][1] = tp[1][0] = tp[1][1] = 0.f;
#pragma unroll
    for (int k2 = 0; k2 < 2; ++k2)
#pragma unroll
        for (int kk = 0; kk < 2; ++kk)
#pragma unroll
            for (int jj = 0; jj < 4; ++jj) {
                const int k = 2 * k2 + kk;
                const int r = 4 * k + jj;       // static
                const int g = k2;               // static
                float av = att_s[head][16 * g + 8 * kk + 4 * q + jj];
                tp[0][g] = fmaf(acc0[r], av, tp[0][g]);
                tp[1][g] = fmaf(acc1[r], av, tp[1][g]);
            }
#pragma unroll
    for (int nt = 0; nt < 2; ++nt)
#pragma unroll
        for (int g = 0; g < 2; ++g) {
            float s = tp[nt][g] + __shfl_xor(tp[nt][g], 32, 64);
            if (q == 0) outp_s[head][g][64 * strip + 32 * nt + lm] = gelu_exact(s);
        }
    __syncthreads();

    if (t < 512) {
        int g = t >> 8, col = t & 255;
        float s = outp_s[0][g][col] + outp_s[1][g][col] + outp_s[2][g][col] + outp_s[3][g][col];
        out[((size_t)blockIdx.x * 2 + g) * 256 + col] = 0.25f * s;
    }
}

extern "C" void kernel_launch(void* const* d_in, const int* in_sizes, int n_in,
                              void* d_out, int out_size, void* d_ws, size_t ws_size,
                              hipStream_t stream) {
    const float* x  = (const float*)d_in[0];
    const float* W0 = (const float*)d_in[1];
    const float* A0 = (const float*)d_in[2];
    const float* W1 = (const float*)d_in[3];
    const float* A1 = (const float*)d_in[4];

    char* ws = (char*)d_ws;
    float*  y1   = (float*)ws;                  // 8 MiB: [8192][256]
    half_t* Wsw0 = (half_t*)(ws + 8388608);     // 512 KiB
    half_t* Wsw1 = (half_t*)(ws + 8912896);     // 512 KiB
    half_t* Zah0 = (half_t*)(ws + 9437184);     // 16 KiB each
    half_t* Zal0 = (half_t*)(ws + 9453568);
    half_t* Zah1 = (half_t*)(ws + 9469952);
    half_t* Zal1 = (half_t*)(ws + 9486336);

    prep<<<64, 256, 0, stream>>>(W0, A0, W1, A1, Wsw0, Wsw1, Zah0, Zal0, Zah1, Zal1);
    gat1t<<<2048, 256, 0, stream>>>(x, Wsw0, Zah0, Zal0, y1);
    gat2<<<256, 1024, 0, stream>>>(y1, Wsw1, Zah1, Zal1, (float*)d_out);
}